// Round 17
// baseline (92.341 us; speedup 1.0000x reference)
//
#include <hip/hip_runtime.h>

#define EMB 512
#define NROWS 10000
#define NPAIRS 65536

typedef __bf16 bf16x8 __attribute__((ext_vector_type(8)));
typedef float  f32x4  __attribute__((ext_vector_type(4)));
typedef unsigned int u32x4 __attribute__((ext_vector_type(4)));

// Split fp32 pair into packed bf16-hi dword and bf16-lo dword (RNE both).
__device__ __forceinline__ void split2(float x0, float x1, unsigned* hw, unsigned* lw) {
    unsigned u0 = __float_as_uint(x0), u1 = __float_as_uint(x1);
    unsigned r0 = u0 + 0x7FFFu + ((u0 >> 16) & 1u);
    unsigned r1 = u1 + 0x7FFFu + ((u1 >> 16) & 1u);
    float h0 = __uint_as_float(r0 & 0xFFFF0000u);
    float h1 = __uint_as_float(r1 & 0xFFFF0000u);
    float l0 = x0 - h0, l1 = x1 - h1;                 // exact
    unsigned v0 = __float_as_uint(l0), v1 = __float_as_uint(l1);
    unsigned s0 = v0 + 0x7FFFu + ((v0 >> 16) & 1u);
    unsigned s1 = v1 + 0x7FFFu + ((v1 >> 16) & 1u);
    *hw = (r0 >> 16) | (r1 & 0xFFFF0000u);
    *lw = (s0 >> 16) | (s1 & 0xFFFF0000u);
}

// ---------------- Kernel 0: pre-fragment W1 and W2 into MFMA lane-order bf16 hi/lo ----------
__global__ __launch_bounds__(256)
void k0_fragment(const float* __restrict__ W1, const float* __restrict__ W2,
                 unsigned short* __restrict__ W1Fhi, unsigned short* __restrict__ W1Flo,
                 unsigned short* __restrict__ W2Fhi, unsigned short* __restrict__ W2Flo)
{
    int e = blockIdx.x * 256 + threadIdx.x;
    float x;
    unsigned short *hp, *lp;
    if (e < 131072) {
        int i  = e & 7;
        int l  = (e >> 3) & 63;
        int nt = (e >> 9) & 7;
        int kt = (e >> 12) & 15;
        int t  = e >> 16;
        int k = kt * 32 + 8 * (l >> 4) + i;
        int n = nt * 16 + (l & 15);
        x = W1[(t * 512 + k) * 128 + n];
        hp = W1Fhi + e; lp = W1Flo + e;
    } else {
        int e2 = e - 131072;
        int i  = e2 & 7;
        int l  = (e2 >> 3) & 63;
        int nt = (e2 >> 9) & 3;
        int kt = e2 >> 11;
        int k = kt * 32 + 8 * (l >> 4) + i;
        int n = nt * 16 + (l & 15);
        x = W2[k * 64 + n];
        hp = W2Fhi + e2; lp = W2Flo + e2;
    }
    unsigned u = __float_as_uint(x);
    unsigned r = u + 0x7FFFu + ((u >> 16) & 1u);
    float hf = __uint_as_float(r & 0xFFFF0000u);
    float lf = x - hf;
    unsigned v = __float_as_uint(lf);
    unsigned s = v + 0x7FFFu + ((v >> 16) & 1u);
    *hp = (unsigned short)(r >> 16);
    *lp = (unsigned short)(s >> 16);
}

// ---------------- Kernel 0b: pre-split BOTH embedding tables to linear bf16 hi/lo ----------
// 10000 blocks x 256. Thread e handles one float4: rows are linear [drug | tgt][row][k].
// Read 41 MB + write 41 MB, fully coalesced (8B stores) -> HBM-BW-bound (~14 us).
__global__ __launch_bounds__(256)
void k0b_split(const float* __restrict__ drug, const float* __restrict__ tgt,
               unsigned short* __restrict__ EHi, unsigned short* __restrict__ ELo)
{
    int e = blockIdx.x * 256 + threadIdx.x;      // float4 index, 0..2559999
    const float* src;
    int off;
    if (e < 1280000) { src = drug; off = e; }
    else             { src = tgt;  off = e - 1280000; }
    float4 v = ((const float4*)src)[off];
    unsigned h01, l01, h23, l23;
    split2(v.x, v.y, &h01, &l01);
    split2(v.z, v.w, &h23, &l23);
    *(uint2*)(EHi + (size_t)e * 4) = make_uint2(h01, h23);
    *(uint2*)(ELo + (size_t)e * 4) = make_uint2(l01, l23);
}

// ---------------- Kernel 1 (pre-split path): pure load->MFMA streaming GEMM ----------------
// 250 blocks (2 tables x 125 rowgroups of 80 rows = 10000 exact) x 512 thr (wave = nt).
// B panel in 128 VGPRs (loaded once). ZERO LDS, ZERO barriers, ZERO VALU in the K-loop:
// per kt {2x16B global A loads (bf16 hi/lo, L1-shared by the block's 8 waves), 3 MFMA}.
__global__ __launch_bounds__(512, 2)
void k1_stream(const unsigned* __restrict__ EHi, const unsigned* __restrict__ ELo,
               const unsigned* __restrict__ W1Fhi, const unsigned* __restrict__ W1Flo,
               const float* __restrict__ b1,
               float* __restrict__ D, float* __restrict__ T)
{
    int bid = blockIdx.x, tid = threadIdx.x;
    bool isT = bid >= 125;
    int rg = isT ? bid - 125 : bid;
    float* out = isT ? T : D;
    int row0 = rg * 80;

    int wave = tid >> 6, lane = tid & 63;
    int g = lane >> 4, lm = lane & 15;
    int nt = wave;

    const u32x4* BH = (const u32x4*)W1Fhi + (isT ? 8192 : 0);
    const u32x4* BL = (const u32x4*)W1Flo + (isT ? 8192 : 0);
    const u32x4* AH = (const u32x4*)EHi + (isT ? (size_t)NROWS * 64 : 0);  // 64 u32x4/row
    const u32x4* AL = (const u32x4*)ELo + (isT ? (size_t)NROWS * 64 : 0);

    // ---- B panel -> registers (32 u32x4 = 128 VGPRs), once ----
    u32x4 bhv[16], blv[16];
    #pragma unroll
    for (int kt = 0; kt < 16; kt++) {
        bhv[kt] = BH[(kt * 8 + nt) * 64 + lane];
        blv[kt] = BL[(kt * 8 + nt) * 64 + lane];
    }
    float bias = isT ? 0.f : b1[nt * 16 + lm];

    #pragma unroll 1
    for (int c = 0; c < 5; c++) {
        int row = row0 + c * 16 + lm;               // exact: 125*80 = 10000
        const u32x4* ah = AH + (size_t)row * 64;
        const u32x4* al = AL + (size_t)row * 64;

        f32x4 acc;
        acc[0] = 0.f; acc[1] = 0.f; acc[2] = 0.f; acc[3] = 0.f;

        #pragma unroll
        for (int kt = 0; kt < 16; kt++) {
            u32x4 ahq = ah[kt * 4 + g];
            u32x4 alq = al[kt * 4 + g];
            bf16x8 Ah = __builtin_bit_cast(bf16x8, ahq);
            bf16x8 Al = __builtin_bit_cast(bf16x8, alq);
            bf16x8 Bh = __builtin_bit_cast(bf16x8, bhv[kt]);
            bf16x8 Bl = __builtin_bit_cast(bf16x8, blv[kt]);
            acc = __builtin_amdgcn_mfma_f32_16x16x32_bf16(Ah, Bh, acc, 0, 0, 0);
            acc = __builtin_amdgcn_mfma_f32_16x16x32_bf16(Ah, Bl, acc, 0, 0, 0);
            acc = __builtin_amdgcn_mfma_f32_16x16x32_bf16(Al, Bh, acc, 0, 0, 0);
        }

        // store: C row = row0 + c*16 + 4g + reg, col = nt*16 + lm (verified map)
        #pragma unroll
        for (int reg = 0; reg < 4; reg++) {
            int r = row0 + c * 16 + 4 * g + reg;
            out[r * 128 + nt * 16 + lm] = acc[reg] + bias;
        }
    }
}

// ---------------- Kernel 1 (fallback, R15 best): B-in-regs streaming with in-kernel split --
#define K1_RPB 79
#define K1_NCH 5

__global__ __launch_bounds__(256, 2)
void k1_mfma(const float* __restrict__ drug, const float* __restrict__ tgt,
             const unsigned* __restrict__ W1Fhi, const unsigned* __restrict__ W1Flo,
             const float* __restrict__ b1,
             float* __restrict__ D, float* __restrict__ T)
{
    __shared__ unsigned short Ah[2][16][512];
    __shared__ unsigned short Al[2][16][512];

    int bid = blockIdx.x, tid = threadIdx.x;
    int t  = bid & 1;
    int ch = (bid >> 1) & 1;
    int rg = bid >> 2;
    const float* emb = t ? tgt : drug;
    float* out = t ? T : D;
    int row_base = rg * K1_RPB;

    int wave = tid >> 6, lane = tid & 63;
    int g = lane >> 4, lm = lane & 15;
    int nt = ch * 4 + wave;

    const u32x4* BH = (const u32x4*)W1Fhi + (t ? 8192 : 0);
    const u32x4* BL = (const u32x4*)W1Flo + (t ? 8192 : 0);

    u32x4 bhv[16], blv[16];
    #pragma unroll
    for (int kt = 0; kt < 16; kt++) {
        bhv[kt] = BH[(kt * 8 + nt) * 64 + lane];
        blv[kt] = BL[(kt * 8 + nt) * 64 + lane];
    }
    float bias = t ? 0.f : b1[nt * 16 + lm];

    float4 va[4][2];
    #pragma unroll
    for (int i = 0; i < 4; i++) {
        int gr = row_base + wave * 4 + i;
        if (gr > NROWS - 1) gr = NROWS - 1;
        const float* src = emb + (size_t)gr * EMB + lane * 8;
        va[i][0] = *(const float4*)src;
        va[i][1] = *(const float4*)(src + 4);
    }

    #pragma unroll
    for (int c = 0; c < K1_NCH; c++) {
        float4 vb[4][2];
        if (c + 1 < K1_NCH) {
            #pragma unroll
            for (int i = 0; i < 4; i++) {
                int gr = row_base + (c + 1) * 16 + wave * 4 + i;
                if (gr > NROWS - 1) gr = NROWS - 1;
                const float* src = emb + (size_t)gr * EMB + lane * 8;
                vb[i][0] = *(const float4*)src;
                vb[i][1] = *(const float4*)(src + 4);
            }
        }
        #pragma unroll
        for (int i = 0; i < 4; i++) {
            int lr = wave * 4 + i;
            unsigned h0, h1, h2, h3, l0, l1, l2, l3;
            split2(va[i][0].x, va[i][0].y, &h0, &l0);
            split2(va[i][0].z, va[i][0].w, &h1, &l1);
            split2(va[i][1].x, va[i][1].y, &h2, &l2);
            split2(va[i][1].z, va[i][1].w, &h3, &l3);
            u32x4 hq, lq;
            hq[0]=h0; hq[1]=h1; hq[2]=h2; hq[3]=h3;
            lq[0]=l0; lq[1]=l1; lq[2]=l2; lq[3]=l3;
            int cc = lane ^ (lr & 7);
            *(u32x4*)((char*)&Ah[c & 1][0][0] + lr * 1024 + cc * 16) = hq;
            *(u32x4*)((char*)&Al[c & 1][0][0] + lr * 1024 + cc * 16) = lq;
        }
        __syncthreads();
        f32x4 acc;
        acc[0]=0.f; acc[1]=0.f; acc[2]=0.f; acc[3]=0.f;
        #pragma unroll
        for (int kt = 0; kt < 16; kt++) {
            int cc = (kt * 4 + g) ^ (lm & 7);
            u32x4 ahq = *(const u32x4*)((const char*)&Ah[c & 1][0][0] + lm * 1024 + cc * 16);
            u32x4 alq = *(const u32x4*)((const char*)&Al[c & 1][0][0] + lm * 1024 + cc * 16);
            bf16x8 Af = __builtin_bit_cast(bf16x8, ahq);
            bf16x8 Alf = __builtin_bit_cast(bf16x8, alq);
            bf16x8 Bh = __builtin_bit_cast(bf16x8, bhv[kt]);
            bf16x8 Bl = __builtin_bit_cast(bf16x8, blv[kt]);
            acc = __builtin_amdgcn_mfma_f32_16x16x32_bf16(Af, Bh, acc, 0, 0, 0);
            acc = __builtin_amdgcn_mfma_f32_16x16x32_bf16(Af, Bl, acc, 0, 0, 0);
            acc = __builtin_amdgcn_mfma_f32_16x16x32_bf16(Alf, Bh, acc, 0, 0, 0);
        }
        #pragma unroll
        for (int reg = 0; reg < 4; reg++) {
            int lr = c * 16 + 4 * g + reg;
            int row = row_base + lr;
            if (lr < K1_RPB && row < NROWS)
                out[row * 128 + nt * 16 + lm] = acc[reg] + bias;
        }
        #pragma unroll
        for (int i = 0; i < 4; i++) { va[i][0] = vb[i][0]; va[i][1] = vb[i][1]; }
    }
}

// ---------------- Kernel 2: pair loss via split-bf16 MFMA, DMA-staged gathers ----------------
__global__ __launch_bounds__(256)
void k2_pairs(const float* __restrict__ D, const float* __restrict__ T,
              const int* __restrict__ pos, const int* __restrict__ neg,
              const unsigned* __restrict__ W2Fhi, const unsigned* __restrict__ W2Flo,
              const float* __restrict__ b2, const float* __restrict__ W3,
              double* __restrict__ partials)
{
    __shared__ u32x4 Ash[4][768];

    int tid = threadIdx.x;
    int wave = tid >> 6, lane = tid & 63;
    int g = lane >> 4, lm = lane & 15;
    int rr = lane >> 3, cc = lane & 7;
    int gw = blockIdx.x * 4 + wave;
    const int* pairs = (gw < 2048) ? pos : neg;
    int p0 = (gw & 2047) * 32;

    const float* bp[12];
    #pragma unroll
    for (int it = 0; it < 12; it++) {
        int pr = it * 8 + rr;
        int idxv;
        const float* src;
        if (pr < 32) { idxv = pairs[(p0 + pr) * 3]; src = D; }
        else { int q = pr - 32; idxv = pairs[(p0 + (q >> 1)) * 3 + 1 + (q & 1)]; src = T; }
        bp[it] = src + (size_t)idxv * 128 + ((cc ^ (pr & 7)) << 2);
    }

    u32x4* A4w = &Ash[wave][0];
    const u32x4* BH4 = (const u32x4*)W2Fhi;
    const u32x4* BL4 = (const u32x4*)W2Flo;

    f32x4 acc[4][4];
    #pragma unroll
    for (int mt = 0; mt < 4; mt++)
        #pragma unroll
        for (int nt = 0; nt < 4; nt++) { acc[mt][nt][0]=0.f; acc[mt][nt][1]=0.f; acc[mt][nt][2]=0.f; acc[mt][nt][3]=0.f; }

    #pragma unroll 1
    for (int kt = 0; kt < 4; kt++) {
        u32x4 bh[4], bl[4];
        #pragma unroll
        for (int nt = 0; nt < 4; nt++) {
            bh[nt] = BH4[(kt * 4 + nt) * 64 + lane];
            bl[nt] = BL4[(kt * 4 + nt) * 64 + lane];
        }
        #pragma unroll
        for (int it = 0; it < 12; it++) {
            __builtin_amdgcn_global_load_lds(
                (const __attribute__((address_space(1))) void*)(bp[it] + kt * 32),
                (__attribute__((address_space(3))) void*)((char*)A4w + it * 1024),
                16, 0, 0);
        }
        asm volatile("s_waitcnt vmcnt(0)" ::: "memory");
        #pragma unroll
        for (int mt = 0; mt < 4; mt++) {
            int r = mt * 16 + lm;
            int p = r >> 1;
            int ds = p & 7, ts = r & 7;
            const f32x4* drow = (const f32x4*)(A4w + p * 8);
            const f32x4* trow = (const f32x4*)(A4w + (32 + r) * 8);
            f32x4 d0 = drow[(2 * g) ^ ds];
            f32x4 d1 = drow[(2 * g + 1) ^ ds];
            f32x4 t0 = trow[(2 * g) ^ ts];
            f32x4 t1 = trow[(2 * g + 1) ^ ts];
            float h0 = fmaxf(d0[0] + t0[0], 0.f), h1v = fmaxf(d0[1] + t0[1], 0.f);
            float h2 = fmaxf(d0[2] + t0[2], 0.f), h3 = fmaxf(d0[3] + t0[3], 0.f);
            float h4 = fmaxf(d1[0] + t1[0], 0.f), h5 = fmaxf(d1[1] + t1[1], 0.f);
            float h6 = fmaxf(d1[2] + t1[2], 0.f), h7 = fmaxf(d1[3] + t1[3], 0.f);
            unsigned hq0, hq1, hq2, hq3, lq0, lq1, lq2, lq3;
            split2(h0, h1v, &hq0, &lq0);
            split2(h2, h3,  &hq1, &lq1);
            split2(h4, h5,  &hq2, &lq2);
            split2(h6, h7,  &hq3, &lq3);
            u32x4 ah, al;
            ah[0]=hq0; ah[1]=hq1; ah[2]=hq2; ah[3]=hq3;
            al[0]=lq0; al[1]=lq1; al[2]=lq2; al[3]=lq3;
            bf16x8 Ahf = __builtin_bit_cast(bf16x8, ah);
            bf16x8 Alf = __builtin_bit_cast(bf16x8, al);
            #pragma unroll
            for (int nt = 0; nt < 4; nt++) {
                bf16x8 Bh = __builtin_bit_cast(bf16x8, bh[nt]);
                bf16x8 Bl = __builtin_bit_cast(bf16x8, bl[nt]);
                acc[mt][nt] = __builtin_amdgcn_mfma_f32_16x16x32_bf16(Ahf, Bh, acc[mt][nt], 0, 0, 0);
                acc[mt][nt] = __builtin_amdgcn_mfma_f32_16x16x32_bf16(Ahf, Bl, acc[mt][nt], 0, 0, 0);
                acc[mt][nt] = __builtin_amdgcn_mfma_f32_16x16x32_bf16(Alf, Bh, acc[mt][nt], 0, 0, 0);
            }
        }
        asm volatile("s_waitcnt lgkmcnt(0)" ::: "memory");
    }

    float b2v[4], w3v[4];
    #pragma unroll
    for (int nt = 0; nt < 4; nt++) { b2v[nt] = b2[nt * 16 + lm]; w3v[nt] = W3[nt * 16 + lm]; }

    float pr[4][4];
    #pragma unroll
    for (int mt = 0; mt < 4; mt++)
        #pragma unroll
        for (int reg = 0; reg < 4; reg++) {
            float s = 0.f;
            #pragma unroll
            for (int nt = 0; nt < 4; nt++) {
                float h2 = fmaxf(acc[mt][nt][reg] + b2v[nt], 0.f);
                s = fmaf(h2, w3v[nt], s);
            }
            pr[mt][reg] = s;
        }
    #pragma unroll
    for (int m = 1; m <= 8; m <<= 1)
        #pragma unroll
        for (int mt = 0; mt < 4; mt++)
            #pragma unroll
            for (int reg = 0; reg < 4; reg++)
                pr[mt][reg] += __shfl_xor(pr[mt][reg], m, 64);

    double dsq = 0.0;
    #pragma unroll
    for (int mt = 0; mt < 4; mt++) {
        float d0 = pr[mt][0] - pr[mt][1];
        float d1 = pr[mt][2] - pr[mt][3];
        dsq += (double)d0 * (double)d0 + (double)d1 * (double)d1;
    }
    dsq += __shfl_xor(dsq, 16, 64);
    dsq += __shfl_xor(dsq, 32, 64);

    __syncthreads();
    if (lane == 0) ((double*)&Ash[wave][0])[0] = dsq;
    __syncthreads();
    if (tid == 0) {
        double sum = 0.0;
        #pragma unroll
        for (int w = 0; w < 4; w++) sum += ((double*)&Ash[w][0])[0];
        partials[blockIdx.x] = sum;
    }
}

// ---------------- Kernel 3: final reduction (1024 partials) ----------------
__global__ void k3_final(const double* __restrict__ partials, float* __restrict__ out)
{
    int lane = threadIdx.x;
    double sp = 0.0, sn = 0.0;
    #pragma unroll
    for (int i = 0; i < 8; i++) {
        sp += partials[lane + 64 * i];
        sn += partials[512 + lane + 64 * i];
    }
    #pragma unroll
    for (int m = 1; m <= 32; m <<= 1) {
        sp += __shfl_xor(sp, m, 64);
        sn += __shfl_xor(sn, m, 64);
    }
    if (lane == 0) out[0] = (float)((sp - sn) / (double)NPAIRS);
}

extern "C" void kernel_launch(void* const* d_in, const int* in_sizes, int n_in,
                              void* d_out, int out_size, void* d_ws, size_t ws_size,
                              hipStream_t stream) {
    const int*   pos  = (const int*)d_in[0];
    const int*   neg  = (const int*)d_in[1];
    const float* drug = (const float*)d_in[2];
    const float* tgt  = (const float*)d_in[3];
    const float* W1   = (const float*)d_in[4];
    const float* b1   = (const float*)d_in[5];
    const float* W2   = (const float*)d_in[6];
    const float* b2   = (const float*)d_in[7];
    const float* W3   = (const float*)d_in[8];
    // d_in[9] = b3: cancels in a1 - a2, unused

    float* Dp = (float*)d_ws;                                 // 5.12 MB
    float* Tp = Dp + NROWS * 128;                             // 5.12 MB
    char* base = (char*)(Tp + NROWS * 128);
    unsigned short* W2Fhi = (unsigned short*)base;            // 16 KB
    unsigned short* W2Flo = W2Fhi + 8192;                     // 16 KB
    unsigned short* W1Fhi = W2Flo + 8192;                     // 256 KB
    unsigned short* W1Flo = W1Fhi + 131072;                   // 256 KB
    double* partials = (double*)(W1Flo + 131072);             // 8 KB
    unsigned short* EHi = (unsigned short*)(partials + 1024); // 20.5 MB
    unsigned short* ELo = EHi + 2 * NROWS * EMB;              // 20.5 MB
    float* out = (float*)d_out;

    size_t need = (size_t)((char*)(ELo + 2 * NROWS * EMB) - (char*)d_ws);
    bool presplit = ws_size >= need;

    k0_fragment<<<544, 256, 0, stream>>>(W1, W2, W1Fhi, W1Flo, W2Fhi, W2Flo);
    if (presplit) {
        k0b_split<<<10000, 256, 0, stream>>>(drug, tgt, EHi, ELo);
        k1_stream<<<250, 512, 0, stream>>>((const unsigned*)EHi, (const unsigned*)ELo,
                                           (const unsigned*)W1Fhi, (const unsigned*)W1Flo,
                                           b1, Dp, Tp);
    } else {
        k1_mfma<<<512, 256, 0, stream>>>(drug, tgt, (const unsigned*)W1Fhi,
                                         (const unsigned*)W1Flo, b1, Dp, Tp);
    }
    k2_pairs<<<1024, 256, 0, stream>>>(Dp, Tp, pos, neg, (const unsigned*)W2Fhi,
                                       (const unsigned*)W2Flo, b2, W3, partials);
    k3_final<<<1, 64, 0, stream>>>(partials, out);
}

// Round 18
// 60.596 us; speedup vs baseline: 1.5239x; 1.5239x over previous
//
#include <hip/hip_runtime.h>

#define EMB 512
#define NROWS 10000
#define NPAIRS 65536

typedef __bf16 bf16x8 __attribute__((ext_vector_type(8)));
typedef float  f32x4  __attribute__((ext_vector_type(4)));
typedef unsigned int u32x4 __attribute__((ext_vector_type(4)));

// Split fp32 pair into packed bf16-hi dword and bf16-lo dword (RNE both).
__device__ __forceinline__ void split2(float x0, float x1, unsigned* hw, unsigned* lw) {
    unsigned u0 = __float_as_uint(x0), u1 = __float_as_uint(x1);
    unsigned r0 = u0 + 0x7FFFu + ((u0 >> 16) & 1u);
    unsigned r1 = u1 + 0x7FFFu + ((u1 >> 16) & 1u);
    float h0 = __uint_as_float(r0 & 0xFFFF0000u);
    float h1 = __uint_as_float(r1 & 0xFFFF0000u);
    float l0 = x0 - h0, l1 = x1 - h1;                 // exact
    unsigned v0 = __float_as_uint(l0), v1 = __float_as_uint(l1);
    unsigned s0 = v0 + 0x7FFFu + ((v0 >> 16) & 1u);
    unsigned s1 = v1 + 0x7FFFu + ((v1 >> 16) & 1u);
    *hw = (r0 >> 16) | (r1 & 0xFFFF0000u);
    *lw = (s0 >> 16) | (s1 & 0xFFFF0000u);
}

// ---------------- Kernel 0: pre-fragment W1 and W2 into MFMA lane-order bf16 hi/lo ----------
__global__ __launch_bounds__(256)
void k0_fragment(const float* __restrict__ W1, const float* __restrict__ W2,
                 unsigned short* __restrict__ W1Fhi, unsigned short* __restrict__ W1Flo,
                 unsigned short* __restrict__ W2Fhi, unsigned short* __restrict__ W2Flo)
{
    int e = blockIdx.x * 256 + threadIdx.x;
    float x;
    unsigned short *hp, *lp;
    if (e < 131072) {
        int i  = e & 7;
        int l  = (e >> 3) & 63;
        int nt = (e >> 9) & 7;
        int kt = (e >> 12) & 15;
        int t  = e >> 16;
        int k = kt * 32 + 8 * (l >> 4) + i;
        int n = nt * 16 + (l & 15);
        x = W1[(t * 512 + k) * 128 + n];
        hp = W1Fhi + e; lp = W1Flo + e;
    } else {
        int e2 = e - 131072;
        int i  = e2 & 7;
        int l  = (e2 >> 3) & 63;
        int nt = (e2 >> 9) & 3;
        int kt = e2 >> 11;
        int k = kt * 32 + 8 * (l >> 4) + i;
        int n = nt * 16 + (l & 15);
        x = W2[k * 64 + n];
        hp = W2Fhi + e2; lp = W2Flo + e2;
    }
    unsigned u = __float_as_uint(x);
    unsigned r = u + 0x7FFFu + ((u >> 16) & 1u);
    float hf = __uint_as_float(r & 0xFFFF0000u);
    float lf = x - hf;
    unsigned v = __float_as_uint(lf);
    unsigned s = v + 0x7FFFu + ((v >> 16) & 1u);
    *hp = (unsigned short)(r >> 16);
    *lp = (unsigned short)(s >> 16);
}

// ---------------- Kernel 1: D = drug @ W1[:512,:] + b1, T = tgt @ W1[512:,:] ----------------
// k2-CLONE structure (the session's only measured-fast shape): 1250 blocks x 4 INDEPENDENT
// waves (5000 waves ~ 5/SIMD). Wave = 16 rows x 32 cols (ntb = 2*wave). Per kt:
// {4 B-frag global loads + 2 A-row DMAs (fp32, src chunk pre-swizzled cc^(pr&7), k2's
// proven pattern)} -> vmcnt(0) -> 2 conflict-free ds_read_b128 -> in-reg split -> 6 MFMA
// -> lgkmcnt(0). Per-wave chain = 16 latency exposures (vs R17's 80). 8 KB LDS/block.
#define K1_TILES 625   // 16-row groups per table; 625*16 = 10000 exact

__global__ __launch_bounds__(256)
void k1_dma(const float* __restrict__ drug, const float* __restrict__ tgt,
            const unsigned* __restrict__ W1Fhi, const unsigned* __restrict__ W1Flo,
            const float* __restrict__ b1,
            float* __restrict__ D, float* __restrict__ T)
{
    __shared__ u32x4 Abuf[4][128];   // 8 KB: per-wave 2 KB = 16 rows x 8 chunks x 16 B

    int bid = blockIdx.x, tid = threadIdx.x;
    bool isT = bid >= K1_TILES;
    int rt = isT ? bid - K1_TILES : bid;
    const float* emb = isT ? tgt : drug;
    float* out = isT ? T : D;
    int row0 = rt * 16;

    int wave = tid >> 6, lane = tid & 63;
    int g = lane >> 4, lm = lane & 15;
    int rr = lane >> 3, cc = lane & 7;
    int ntb = wave * 2;                  // this wave's 2 N-tiles
    int rk = lm & 7;                     // read swizzle key

    const u32x4* BH = (const u32x4*)W1Fhi + (isT ? 8192 : 0);
    const u32x4* BL = (const u32x4*)W1Flo + (isT ? 8192 : 0);

    // DMA it covers rows pr = it*8 + rr, chunk cc (dest linear; source pre-swizzled)
    const float* sp[2];
    #pragma unroll
    for (int it = 0; it < 2; it++) {
        int pr = it * 8 + rr;
        sp[it] = emb + (size_t)(row0 + pr) * EMB + ((cc ^ (pr & 7)) << 2);
    }

    u32x4* A4w = &Abuf[wave][0];

    f32x4 acc[2];
    #pragma unroll
    for (int j = 0; j < 2; j++) { acc[j][0]=0.f; acc[j][1]=0.f; acc[j][2]=0.f; acc[j][3]=0.f; }

    #pragma unroll 1
    for (int kt = 0; kt < 16; kt++) {
        // B fragments first (L2-warm), then the A DMAs — all drained by one vmcnt(0)
        u32x4 bh0 = BH[(kt * 8 + ntb) * 64 + lane];
        u32x4 bh1 = BH[(kt * 8 + ntb + 1) * 64 + lane];
        u32x4 bl0 = BL[(kt * 8 + ntb) * 64 + lane];
        u32x4 bl1 = BL[(kt * 8 + ntb + 1) * 64 + lane];
        #pragma unroll
        for (int it = 0; it < 2; it++) {
            __builtin_amdgcn_global_load_lds(
                (const __attribute__((address_space(1))) void*)(sp[it] + kt * 32),
                (__attribute__((address_space(3))) void*)((char*)A4w + it * 1024),
                16, 0, 0);
        }
        asm volatile("s_waitcnt vmcnt(0)" ::: "memory");
        const f32x4* Af = (const f32x4*)A4w;
        f32x4 a0 = Af[lm * 8 + ((2 * g)     ^ rk)];
        f32x4 a1 = Af[lm * 8 + ((2 * g + 1) ^ rk)];
        unsigned h0, h1, h2, h3, l0, l1, l2, l3;
        split2(a0[0], a0[1], &h0, &l0);
        split2(a0[2], a0[3], &h1, &l1);
        split2(a1[0], a1[1], &h2, &l2);
        split2(a1[2], a1[3], &h3, &l3);
        u32x4 ah, al;
        ah[0]=h0; ah[1]=h1; ah[2]=h2; ah[3]=h3;
        al[0]=l0; al[1]=l1; al[2]=l2; al[3]=l3;
        bf16x8 Ah = __builtin_bit_cast(bf16x8, ah);
        bf16x8 Al = __builtin_bit_cast(bf16x8, al);
        bf16x8 Bh0 = __builtin_bit_cast(bf16x8, bh0);
        bf16x8 Bh1 = __builtin_bit_cast(bf16x8, bh1);
        bf16x8 Bl0 = __builtin_bit_cast(bf16x8, bl0);
        bf16x8 Bl1 = __builtin_bit_cast(bf16x8, bl1);
        acc[0] = __builtin_amdgcn_mfma_f32_16x16x32_bf16(Ah, Bh0, acc[0], 0, 0, 0);
        acc[1] = __builtin_amdgcn_mfma_f32_16x16x32_bf16(Ah, Bh1, acc[1], 0, 0, 0);
        acc[0] = __builtin_amdgcn_mfma_f32_16x16x32_bf16(Ah, Bl0, acc[0], 0, 0, 0);
        acc[1] = __builtin_amdgcn_mfma_f32_16x16x32_bf16(Ah, Bl1, acc[1], 0, 0, 0);
        acc[0] = __builtin_amdgcn_mfma_f32_16x16x32_bf16(Al, Bh0, acc[0], 0, 0, 0);
        acc[1] = __builtin_amdgcn_mfma_f32_16x16x32_bf16(Al, Bh1, acc[1], 0, 0, 0);
        asm volatile("s_waitcnt lgkmcnt(0)" ::: "memory");  // LDS reads retired before next DMA
    }

    // store: C row = row0 + 4g + reg, col = (ntb+j)*16 + lm (verified map); exact fit
    #pragma unroll
    for (int j = 0; j < 2; j++) {
        int col = (ntb + j) * 16 + lm;
        float bias = isT ? 0.f : b1[col];
        #pragma unroll
        for (int reg = 0; reg < 4; reg++) {
            int row = row0 + 4 * g + reg;
            out[row * 128 + col] = acc[j][reg] + bias;
        }
    }
}

// ---------------- Kernel 2: pair loss via split-bf16 MFMA, DMA-staged gathers ----------------
// R6 structure (measured best ~19us): 1024 blocks x 4 independent waves, 32 pairs/wave,
// per-kt 12x global_load_lds burst + vmcnt(0), wave-private 12 KB.
__global__ __launch_bounds__(256)
void k2_pairs(const float* __restrict__ D, const float* __restrict__ T,
              const int* __restrict__ pos, const int* __restrict__ neg,
              const unsigned* __restrict__ W2Fhi, const unsigned* __restrict__ W2Flo,
              const float* __restrict__ b2, const float* __restrict__ W3,
              double* __restrict__ partials)
{
    __shared__ u32x4 Ash[4][768];

    int tid = threadIdx.x;
    int wave = tid >> 6, lane = tid & 63;
    int g = lane >> 4, lm = lane & 15;
    int rr = lane >> 3, cc = lane & 7;
    int gw = blockIdx.x * 4 + wave;
    const int* pairs = (gw < 2048) ? pos : neg;
    int p0 = (gw & 2047) * 32;

    const float* bp[12];
    #pragma unroll
    for (int it = 0; it < 12; it++) {
        int pr = it * 8 + rr;
        int idxv;
        const float* src;
        if (pr < 32) { idxv = pairs[(p0 + pr) * 3]; src = D; }
        else { int q = pr - 32; idxv = pairs[(p0 + (q >> 1)) * 3 + 1 + (q & 1)]; src = T; }
        bp[it] = src + (size_t)idxv * 128 + ((cc ^ (pr & 7)) << 2);
    }

    u32x4* A4w = &Ash[wave][0];
    const u32x4* BH4 = (const u32x4*)W2Fhi;
    const u32x4* BL4 = (const u32x4*)W2Flo;

    f32x4 acc[4][4];
    #pragma unroll
    for (int mt = 0; mt < 4; mt++)
        #pragma unroll
        for (int nt = 0; nt < 4; nt++) { acc[mt][nt][0]=0.f; acc[mt][nt][1]=0.f; acc[mt][nt][2]=0.f; acc[mt][nt][3]=0.f; }

    #pragma unroll 1
    for (int kt = 0; kt < 4; kt++) {
        u32x4 bh[4], bl[4];
        #pragma unroll
        for (int nt = 0; nt < 4; nt++) {
            bh[nt] = BH4[(kt * 4 + nt) * 64 + lane];
            bl[nt] = BL4[(kt * 4 + nt) * 64 + lane];
        }
        #pragma unroll
        for (int it = 0; it < 12; it++) {
            __builtin_amdgcn_global_load_lds(
                (const __attribute__((address_space(1))) void*)(bp[it] + kt * 32),
                (__attribute__((address_space(3))) void*)((char*)A4w + it * 1024),
                16, 0, 0);
        }
        asm volatile("s_waitcnt vmcnt(0)" ::: "memory");
        #pragma unroll
        for (int mt = 0; mt < 4; mt++) {
            int r = mt * 16 + lm;
            int p = r >> 1;
            int ds = p & 7, ts = r & 7;
            const f32x4* drow = (const f32x4*)(A4w + p * 8);
            const f32x4* trow = (const f32x4*)(A4w + (32 + r) * 8);
            f32x4 d0 = drow[(2 * g) ^ ds];
            f32x4 d1 = drow[(2 * g + 1) ^ ds];
            f32x4 t0 = trow[(2 * g) ^ ts];
            f32x4 t1 = trow[(2 * g + 1) ^ ts];
            float h0 = fmaxf(d0[0] + t0[0], 0.f), h1v = fmaxf(d0[1] + t0[1], 0.f);
            float h2 = fmaxf(d0[2] + t0[2], 0.f), h3 = fmaxf(d0[3] + t0[3], 0.f);
            float h4 = fmaxf(d1[0] + t1[0], 0.f), h5 = fmaxf(d1[1] + t1[1], 0.f);
            float h6 = fmaxf(d1[2] + t1[2], 0.f), h7 = fmaxf(d1[3] + t1[3], 0.f);
            unsigned hq0, hq1, hq2, hq3, lq0, lq1, lq2, lq3;
            split2(h0, h1v, &hq0, &lq0);
            split2(h2, h3,  &hq1, &lq1);
            split2(h4, h5,  &hq2, &lq2);
            split2(h6, h7,  &hq3, &lq3);
            u32x4 ah, al;
            ah[0]=hq0; ah[1]=hq1; ah[2]=hq2; ah[3]=hq3;
            al[0]=lq0; al[1]=lq1; al[2]=lq2; al[3]=lq3;
            bf16x8 Ahf = __builtin_bit_cast(bf16x8, ah);
            bf16x8 Alf = __builtin_bit_cast(bf16x8, al);
            #pragma unroll
            for (int nt = 0; nt < 4; nt++) {
                bf16x8 Bh = __builtin_bit_cast(bf16x8, bh[nt]);
                bf16x8 Bl = __builtin_bit_cast(bf16x8, bl[nt]);
                acc[mt][nt] = __builtin_amdgcn_mfma_f32_16x16x32_bf16(Ahf, Bh, acc[mt][nt], 0, 0, 0);
                acc[mt][nt] = __builtin_amdgcn_mfma_f32_16x16x32_bf16(Ahf, Bl, acc[mt][nt], 0, 0, 0);
                acc[mt][nt] = __builtin_amdgcn_mfma_f32_16x16x32_bf16(Alf, Bh, acc[mt][nt], 0, 0, 0);
            }
        }
        asm volatile("s_waitcnt lgkmcnt(0)" ::: "memory");
    }

    float b2v[4], w3v[4];
    #pragma unroll
    for (int nt = 0; nt < 4; nt++) { b2v[nt] = b2[nt * 16 + lm]; w3v[nt] = W3[nt * 16 + lm]; }

    float pr[4][4];
    #pragma unroll
    for (int mt = 0; mt < 4; mt++)
        #pragma unroll
        for (int reg = 0; reg < 4; reg++) {
            float s = 0.f;
            #pragma unroll
            for (int nt = 0; nt < 4; nt++) {
                float h2 = fmaxf(acc[mt][nt][reg] + b2v[nt], 0.f);
                s = fmaf(h2, w3v[nt], s);
            }
            pr[mt][reg] = s;
        }
    #pragma unroll
    for (int m = 1; m <= 8; m <<= 1)
        #pragma unroll
        for (int mt = 0; mt < 4; mt++)
            #pragma unroll
            for (int reg = 0; reg < 4; reg++)
                pr[mt][reg] += __shfl_xor(pr[mt][reg], m, 64);

    double dsq = 0.0;
    #pragma unroll
    for (int mt = 0; mt < 4; mt++) {
        float d0 = pr[mt][0] - pr[mt][1];
        float d1 = pr[mt][2] - pr[mt][3];
        dsq += (double)d0 * (double)d0 + (double)d1 * (double)d1;
    }
    dsq += __shfl_xor(dsq, 16, 64);
    dsq += __shfl_xor(dsq, 32, 64);

    __syncthreads();
    if (lane == 0) ((double*)&Ash[wave][0])[0] = dsq;
    __syncthreads();
    if (tid == 0) {
        double sum = 0.0;
        #pragma unroll
        for (int w = 0; w < 4; w++) sum += ((double*)&Ash[w][0])[0];
        partials[blockIdx.x] = sum;
    }
}

// ---------------- Kernel 3: final reduction (1024 partials) ----------------
__global__ void k3_final(const double* __restrict__ partials, float* __restrict__ out)
{
    int lane = threadIdx.x;
    double sp = 0.0, sn = 0.0;
    #pragma unroll
    for (int i = 0; i < 8; i++) {
        sp += partials[lane + 64 * i];
        sn += partials[512 + lane + 64 * i];
    }
    #pragma unroll
    for (int m = 1; m <= 32; m <<= 1) {
        sp += __shfl_xor(sp, m, 64);
        sn += __shfl_xor(sn, m, 64);
    }
    if (lane == 0) out[0] = (float)((sp - sn) / (double)NPAIRS);
}

extern "C" void kernel_launch(void* const* d_in, const int* in_sizes, int n_in,
                              void* d_out, int out_size, void* d_ws, size_t ws_size,
                              hipStream_t stream) {
    const int*   pos  = (const int*)d_in[0];
    const int*   neg  = (const int*)d_in[1];
    const float* drug = (const float*)d_in[2];
    const float* tgt  = (const float*)d_in[3];
    const float* W1   = (const float*)d_in[4];
    const float* b1   = (const float*)d_in[5];
    const float* W2   = (const float*)d_in[6];
    const float* b2   = (const float*)d_in[7];
    const float* W3   = (const float*)d_in[8];
    // d_in[9] = b3: cancels in a1 - a2, unused

    float* Dp = (float*)d_ws;                                 // 5.12 MB
    float* Tp = Dp + NROWS * 128;                             // 5.12 MB
    char* base = (char*)(Tp + NROWS * 128);
    unsigned short* W2Fhi = (unsigned short*)base;            // 16 KB
    unsigned short* W2Flo = W2Fhi + 8192;                     // 16 KB
    unsigned short* W1Fhi = W2Flo + 8192;                     // 256 KB
    unsigned short* W1Flo = W1Fhi + 131072;                   // 256 KB
    double* partials = (double*)(W1Flo + 131072);             // 8 KB
    float* out = (float*)d_out;

    k0_fragment<<<544, 256, 0, stream>>>(W1, W2, W1Fhi, W1Flo, W2Fhi, W2Flo);
    k1_dma<<<2 * K1_TILES, 256, 0, stream>>>(drug, tgt, (const unsigned*)W1Fhi,
                                             (const unsigned*)W1Flo, b1, Dp, Tp);
    k2_pairs<<<1024, 256, 0, stream>>>(Dp, Tp, pos, neg, (const unsigned*)W2Fhi,
                                       (const unsigned*)W2Flo, b2, W3, partials);
    k3_final<<<1, 64, 0, stream>>>(partials, out);
}

// Round 19
// 59.857 us; speedup vs baseline: 1.5427x; 1.0123x over previous
//
#include <hip/hip_runtime.h>

#define EMB 512
#define NROWS 10000
#define NPAIRS 65536

typedef __bf16 bf16x8 __attribute__((ext_vector_type(8)));
typedef float  f32x4  __attribute__((ext_vector_type(4)));
typedef unsigned int u32x4 __attribute__((ext_vector_type(4)));

// Split fp32 pair into packed bf16-hi dword and bf16-lo dword (RNE both).
__device__ __forceinline__ void split2(float x0, float x1, unsigned* hw, unsigned* lw) {
    unsigned u0 = __float_as_uint(x0), u1 = __float_as_uint(x1);
    unsigned r0 = u0 + 0x7FFFu + ((u0 >> 16) & 1u);
    unsigned r1 = u1 + 0x7FFFu + ((u1 >> 16) & 1u);
    float h0 = __uint_as_float(r0 & 0xFFFF0000u);
    float h1 = __uint_as_float(r1 & 0xFFFF0000u);
    float l0 = x0 - h0, l1 = x1 - h1;                 // exact
    unsigned v0 = __float_as_uint(l0), v1 = __float_as_uint(l1);
    unsigned s0 = v0 + 0x7FFFu + ((v0 >> 16) & 1u);
    unsigned s1 = v1 + 0x7FFFu + ((v1 >> 16) & 1u);
    *hw = (r0 >> 16) | (r1 & 0xFFFF0000u);
    *lw = (s0 >> 16) | (s1 & 0xFFFF0000u);
}

// ---------------- Kernel 0: pre-fragment W1 and W2 into MFMA lane-order bf16 hi/lo ----------
__global__ __launch_bounds__(256)
void k0_fragment(const float* __restrict__ W1, const float* __restrict__ W2,
                 unsigned short* __restrict__ W1Fhi, unsigned short* __restrict__ W1Flo,
                 unsigned short* __restrict__ W2Fhi, unsigned short* __restrict__ W2Flo)
{
    int e = blockIdx.x * 256 + threadIdx.x;
    float x;
    unsigned short *hp, *lp;
    if (e < 131072) {
        int i  = e & 7;
        int l  = (e >> 3) & 63;
        int nt = (e >> 9) & 7;
        int kt = (e >> 12) & 15;
        int t  = e >> 16;
        int k = kt * 32 + 8 * (l >> 4) + i;
        int n = nt * 16 + (l & 15);
        x = W1[(t * 512 + k) * 128 + n];
        hp = W1Fhi + e; lp = W1Flo + e;
    } else {
        int e2 = e - 131072;
        int i  = e2 & 7;
        int l  = (e2 >> 3) & 63;
        int nt = (e2 >> 9) & 3;
        int kt = e2 >> 11;
        int k = kt * 32 + 8 * (l >> 4) + i;
        int n = nt * 16 + (l & 15);
        x = W2[k * 64 + n];
        hp = W2Fhi + e2; lp = W2Flo + e2;
    }
    unsigned u = __float_as_uint(x);
    unsigned r = u + 0x7FFFu + ((u >> 16) & 1u);
    float hf = __uint_as_float(r & 0xFFFF0000u);
    float lf = x - hf;
    unsigned v = __float_as_uint(lf);
    unsigned s = v + 0x7FFFu + ((v >> 16) & 1u);
    *hp = (unsigned short)(r >> 16);
    *lp = (unsigned short)(s >> 16);
}

// ---------------- Kernel 1: D = drug @ W1[:512,:] + b1, T = tgt @ W1[512:,:] ----------------
// R18 k2-clone + T3/T4 counted-vmcnt pipeline in the WAVE-PRIVATE regime (no barriers):
// per kt {issue B(kt+1) 4 loads; lgkmcnt(0); issue DMA(kt+1) 2 into dbuf; vmcnt(6) — kt's
// 6 ops drained, kt+1's 6 stay in flight; ds_read buf[kt&1]; split; 6 MFMA}. Fully
// unrolled (static dbuf indices). 1250 blocks x 4 independent waves, 16 KB LDS/block.
#define K1_TILES 625   // 16-row groups per table; 625*16 = 10000 exact

__global__ __launch_bounds__(256)
void k1_pipe(const float* __restrict__ drug, const float* __restrict__ tgt,
             const unsigned* __restrict__ W1Fhi, const unsigned* __restrict__ W1Flo,
             const float* __restrict__ b1,
             float* __restrict__ D, float* __restrict__ T)
{
    __shared__ u32x4 Abuf[4][2][128];   // 16 KB: per-wave 2 x 2 KB (16 rows x 8 chunks x 16 B)

    int bid = blockIdx.x, tid = threadIdx.x;
    bool isT = bid >= K1_TILES;
    int rt = isT ? bid - K1_TILES : bid;
    const float* emb = isT ? tgt : drug;
    float* out = isT ? T : D;
    int row0 = rt * 16;

    int wave = tid >> 6, lane = tid & 63;
    int g = lane >> 4, lm = lane & 15;
    int rr = lane >> 3, cc = lane & 7;
    int ntb = wave * 2;                  // this wave's 2 N-tiles
    int rk = lm & 7;                     // read swizzle key

    const u32x4* BH = (const u32x4*)W1Fhi + (isT ? 8192 : 0);
    const u32x4* BL = (const u32x4*)W1Flo + (isT ? 8192 : 0);

    // DMA it covers rows pr = it*8 + rr, chunk cc (dest linear; source pre-swizzled)
    const float* sp[2];
    #pragma unroll
    for (int it = 0; it < 2; it++) {
        int pr = it * 8 + rr;
        sp[it] = emb + (size_t)(row0 + pr) * EMB + ((cc ^ (pr & 7)) << 2);
    }

    f32x4 acc[2];
    #pragma unroll
    for (int j = 0; j < 2; j++) { acc[j][0]=0.f; acc[j][1]=0.f; acc[j][2]=0.f; acc[j][3]=0.f; }

    // ---- prologue: B(0) + DMA(0) -> 6 ops in flight ----
    u32x4 bh0c = BH[(0 * 8 + ntb) * 64 + lane];
    u32x4 bh1c = BH[(0 * 8 + ntb + 1) * 64 + lane];
    u32x4 bl0c = BL[(0 * 8 + ntb) * 64 + lane];
    u32x4 bl1c = BL[(0 * 8 + ntb + 1) * 64 + lane];
    #pragma unroll
    for (int it = 0; it < 2; it++)
        __builtin_amdgcn_global_load_lds(
            (const __attribute__((address_space(1))) void*)(sp[it]),
            (__attribute__((address_space(3))) void*)((char*)&Abuf[wave][0][0] + it * 1024),
            16, 0, 0);

    #pragma unroll
    for (int kt = 0; kt < 16; kt++) {
        u32x4 bh0n, bh1n, bl0n, bl1n;
        if (kt < 15) {   // compile-time under full unroll
            bh0n = BH[((kt + 1) * 8 + ntb) * 64 + lane];
            bh1n = BH[((kt + 1) * 8 + ntb + 1) * 64 + lane];
            bl0n = BL[((kt + 1) * 8 + ntb) * 64 + lane];
            bl1n = BL[((kt + 1) * 8 + ntb + 1) * 64 + lane];
            // prior iteration's ds_reads retired (their data already consumed) before
            // DMA(kt+1) can overwrite buf[(kt+1)&1] = the buffer read two iterations ago
            asm volatile("s_waitcnt lgkmcnt(0)" ::: "memory");
            #pragma unroll
            for (int it = 0; it < 2; it++)
                __builtin_amdgcn_global_load_lds(
                    (const __attribute__((address_space(1))) void*)(sp[it] + (kt + 1) * 32),
                    (__attribute__((address_space(3))) void*)((char*)&Abuf[wave][(kt + 1) & 1][0] + it * 1024),
                    16, 0, 0);
            asm volatile("s_waitcnt vmcnt(6)" ::: "memory");  // kt's 6 drained; kt+1's fly
        } else {
            asm volatile("s_waitcnt vmcnt(0)" ::: "memory");
        }
        const f32x4* Af = (const f32x4*)&Abuf[wave][kt & 1][0];
        f32x4 a0 = Af[lm * 8 + ((2 * g)     ^ rk)];
        f32x4 a1 = Af[lm * 8 + ((2 * g + 1) ^ rk)];
        unsigned h0, h1, h2, h3, l0, l1, l2, l3;
        split2(a0[0], a0[1], &h0, &l0);
        split2(a0[2], a0[3], &h1, &l1);
        split2(a1[0], a1[1], &h2, &l2);
        split2(a1[2], a1[3], &h3, &l3);
        u32x4 ah, al;
        ah[0]=h0; ah[1]=h1; ah[2]=h2; ah[3]=h3;
        al[0]=l0; al[1]=l1; al[2]=l2; al[3]=l3;
        bf16x8 Ah = __builtin_bit_cast(bf16x8, ah);
        bf16x8 Al = __builtin_bit_cast(bf16x8, al);
        bf16x8 Bh0 = __builtin_bit_cast(bf16x8, bh0c);
        bf16x8 Bh1 = __builtin_bit_cast(bf16x8, bh1c);
        bf16x8 Bl0 = __builtin_bit_cast(bf16x8, bl0c);
        bf16x8 Bl1 = __builtin_bit_cast(bf16x8, bl1c);
        acc[0] = __builtin_amdgcn_mfma_f32_16x16x32_bf16(Ah, Bh0, acc[0], 0, 0, 0);
        acc[1] = __builtin_amdgcn_mfma_f32_16x16x32_bf16(Ah, Bh1, acc[1], 0, 0, 0);
        acc[0] = __builtin_amdgcn_mfma_f32_16x16x32_bf16(Ah, Bl0, acc[0], 0, 0, 0);
        acc[1] = __builtin_amdgcn_mfma_f32_16x16x32_bf16(Ah, Bl1, acc[1], 0, 0, 0);
        acc[0] = __builtin_amdgcn_mfma_f32_16x16x32_bf16(Al, Bh0, acc[0], 0, 0, 0);
        acc[1] = __builtin_amdgcn_mfma_f32_16x16x32_bf16(Al, Bh1, acc[1], 0, 0, 0);
        // rotate pipeline registers
        bh0c = bh0n; bh1c = bh1n; bl0c = bl0n; bl1c = bl1n;
    }

    // store: C row = row0 + 4g + reg, col = (ntb+j)*16 + lm (verified map); exact fit
    #pragma unroll
    for (int j = 0; j < 2; j++) {
        int col = (ntb + j) * 16 + lm;
        float bias = isT ? 0.f : b1[col];
        #pragma unroll
        for (int reg = 0; reg < 4; reg++) {
            int row = row0 + 4 * g + reg;
            out[row * 128 + col] = acc[j][reg] + bias;
        }
    }
}

// ---------------- Kernel 2: pair loss via split-bf16 MFMA, DMA-staged gathers ----------------
// R6 structure (measured best ~19us): 1024 blocks x 4 independent waves, 32 pairs/wave,
// per-kt 12x global_load_lds burst + vmcnt(0), wave-private 12 KB.
__global__ __launch_bounds__(256)
void k2_pairs(const float* __restrict__ D, const float* __restrict__ T,
              const int* __restrict__ pos, const int* __restrict__ neg,
              const unsigned* __restrict__ W2Fhi, const unsigned* __restrict__ W2Flo,
              const float* __restrict__ b2, const float* __restrict__ W3,
              double* __restrict__ partials)
{
    __shared__ u32x4 Ash[4][768];

    int tid = threadIdx.x;
    int wave = tid >> 6, lane = tid & 63;
    int g = lane >> 4, lm = lane & 15;
    int rr = lane >> 3, cc = lane & 7;
    int gw = blockIdx.x * 4 + wave;
    const int* pairs = (gw < 2048) ? pos : neg;
    int p0 = (gw & 2047) * 32;

    const float* bp[12];
    #pragma unroll
    for (int it = 0; it < 12; it++) {
        int pr = it * 8 + rr;
        int idxv;
        const float* src;
        if (pr < 32) { idxv = pairs[(p0 + pr) * 3]; src = D; }
        else { int q = pr - 32; idxv = pairs[(p0 + (q >> 1)) * 3 + 1 + (q & 1)]; src = T; }
        bp[it] = src + (size_t)idxv * 128 + ((cc ^ (pr & 7)) << 2);
    }

    u32x4* A4w = &Ash[wave][0];
    const u32x4* BH4 = (const u32x4*)W2Fhi;
    const u32x4* BL4 = (const u32x4*)W2Flo;

    f32x4 acc[4][4];
    #pragma unroll
    for (int mt = 0; mt < 4; mt++)
        #pragma unroll
        for (int nt = 0; nt < 4; nt++) { acc[mt][nt][0]=0.f; acc[mt][nt][1]=0.f; acc[mt][nt][2]=0.f; acc[mt][nt][3]=0.f; }

    #pragma unroll 1
    for (int kt = 0; kt < 4; kt++) {
        u32x4 bh[4], bl[4];
        #pragma unroll
        for (int nt = 0; nt < 4; nt++) {
            bh[nt] = BH4[(kt * 4 + nt) * 64 + lane];
            bl[nt] = BL4[(kt * 4 + nt) * 64 + lane];
        }
        #pragma unroll
        for (int it = 0; it < 12; it++) {
            __builtin_amdgcn_global_load_lds(
                (const __attribute__((address_space(1))) void*)(bp[it] + kt * 32),
                (__attribute__((address_space(3))) void*)((char*)A4w + it * 1024),
                16, 0, 0);
        }
        asm volatile("s_waitcnt vmcnt(0)" ::: "memory");
        #pragma unroll
        for (int mt = 0; mt < 4; mt++) {
            int r = mt * 16 + lm;
            int p = r >> 1;
            int ds = p & 7, ts = r & 7;
            const f32x4* drow = (const f32x4*)(A4w + p * 8);
            const f32x4* trow = (const f32x4*)(A4w + (32 + r) * 8);
            f32x4 d0 = drow[(2 * g) ^ ds];
            f32x4 d1 = drow[(2 * g + 1) ^ ds];
            f32x4 t0 = trow[(2 * g) ^ ts];
            f32x4 t1 = trow[(2 * g + 1) ^ ts];
            float h0 = fmaxf(d0[0] + t0[0], 0.f), h1v = fmaxf(d0[1] + t0[1], 0.f);
            float h2 = fmaxf(d0[2] + t0[2], 0.f), h3 = fmaxf(d0[3] + t0[3], 0.f);
            float h4 = fmaxf(d1[0] + t1[0], 0.f), h5 = fmaxf(d1[1] + t1[1], 0.f);
            float h6 = fmaxf(d1[2] + t1[2], 0.f), h7 = fmaxf(d1[3] + t1[3], 0.f);
            unsigned hq0, hq1, hq2, hq3, lq0, lq1, lq2, lq3;
            split2(h0, h1v, &hq0, &lq0);
            split2(h2, h3,  &hq1, &lq1);
            split2(h4, h5,  &hq2, &lq2);
            split2(h6, h7,  &hq3, &lq3);
            u32x4 ah, al;
            ah[0]=hq0; ah[1]=hq1; ah[2]=hq2; ah[3]=hq3;
            al[0]=lq0; al[1]=lq1; al[2]=lq2; al[3]=lq3;
            bf16x8 Ahf = __builtin_bit_cast(bf16x8, ah);
            bf16x8 Alf = __builtin_bit_cast(bf16x8, al);
            #pragma unroll
            for (int nt = 0; nt < 4; nt++) {
                bf16x8 Bh = __builtin_bit_cast(bf16x8, bh[nt]);
                bf16x8 Bl = __builtin_bit_cast(bf16x8, bl[nt]);
                acc[mt][nt] = __builtin_amdgcn_mfma_f32_16x16x32_bf16(Ahf, Bh, acc[mt][nt], 0, 0, 0);
                acc[mt][nt] = __builtin_amdgcn_mfma_f32_16x16x32_bf16(Ahf, Bl, acc[mt][nt], 0, 0, 0);
                acc[mt][nt] = __builtin_amdgcn_mfma_f32_16x16x32_bf16(Alf, Bh, acc[mt][nt], 0, 0, 0);
            }
        }
        asm volatile("s_waitcnt lgkmcnt(0)" ::: "memory");
    }

    float b2v[4], w3v[4];
    #pragma unroll
    for (int nt = 0; nt < 4; nt++) { b2v[nt] = b2[nt * 16 + lm]; w3v[nt] = W3[nt * 16 + lm]; }

    float pr[4][4];
    #pragma unroll
    for (int mt = 0; mt < 4; mt++)
        #pragma unroll
        for (int reg = 0; reg < 4; reg++) {
            float s = 0.f;
            #pragma unroll
            for (int nt = 0; nt < 4; nt++) {
                float h2 = fmaxf(acc[mt][nt][reg] + b2v[nt], 0.f);
                s = fmaf(h2, w3v[nt], s);
            }
            pr[mt][reg] = s;
        }
    #pragma unroll
    for (int m = 1; m <= 8; m <<= 1)
        #pragma unroll
        for (int mt = 0; mt < 4; mt++)
            #pragma unroll
            for (int reg = 0; reg < 4; reg++)
                pr[mt][reg] += __shfl_xor(pr[mt][reg], m, 64);

    double dsq = 0.0;
    #pragma unroll
    for (int mt = 0; mt < 4; mt++) {
        float d0 = pr[mt][0] - pr[mt][1];
        float d1 = pr[mt][2] - pr[mt][3];
        dsq += (double)d0 * (double)d0 + (double)d1 * (double)d1;
    }
    dsq += __shfl_xor(dsq, 16, 64);
    dsq += __shfl_xor(dsq, 32, 64);

    __syncthreads();
    if (lane == 0) ((double*)&Ash[wave][0])[0] = dsq;
    __syncthreads();
    if (tid == 0) {
        double sum = 0.0;
        #pragma unroll
        for (int w = 0; w < 4; w++) sum += ((double*)&Ash[w][0])[0];
        partials[blockIdx.x] = sum;
    }
}

// ---------------- Kernel 3: final reduction (1024 partials) ----------------
__global__ void k3_final(const double* __restrict__ partials, float* __restrict__ out)
{
    int lane = threadIdx.x;
    double sp = 0.0, sn = 0.0;
    #pragma unroll
    for (int i = 0; i < 8; i++) {
        sp += partials[lane + 64 * i];
        sn += partials[512 + lane + 64 * i];
    }
    #pragma unroll
    for (int m = 1; m <= 32; m <<= 1) {
        sp += __shfl_xor(sp, m, 64);
        sn += __shfl_xor(sn, m, 64);
    }
    if (lane == 0) out[0] = (float)((sp - sn) / (double)NPAIRS);
}

extern "C" void kernel_launch(void* const* d_in, const int* in_sizes, int n_in,
                              void* d_out, int out_size, void* d_ws, size_t ws_size,
                              hipStream_t stream) {
    const int*   pos  = (const int*)d_in[0];
    const int*   neg  = (const int*)d_in[1];
    const float* drug = (const float*)d_in[2];
    const float* tgt  = (const float*)d_in[3];
    const float* W1   = (const float*)d_in[4];
    const float* b1   = (const float*)d_in[5];
    const float* W2   = (const float*)d_in[6];
    const float* b2   = (const float*)d_in[7];
    const float* W3   = (const float*)d_in[8];
    // d_in[9] = b3: cancels in a1 - a2, unused

    float* Dp = (float*)d_ws;                                 // 5.12 MB
    float* Tp = Dp + NROWS * 128;                             // 5.12 MB
    char* base = (char*)(Tp + NROWS * 128);
    unsigned short* W2Fhi = (unsigned short*)base;            // 16 KB
    unsigned short* W2Flo = W2Fhi + 8192;                     // 16 KB
    unsigned short* W1Fhi = W2Flo + 8192;                     // 256 KB
    unsigned short* W1Flo = W1Fhi + 131072;                   // 256 KB
    double* partials = (double*)(W1Flo + 131072);             // 8 KB
    float* out = (float*)d_out;

    k0_fragment<<<544, 256, 0, stream>>>(W1, W2, W1Fhi, W1Flo, W2Fhi, W2Flo);
    k1_pipe<<<2 * K1_TILES, 256, 0, stream>>>(drug, tgt, (const unsigned*)W1Fhi,
                                              (const unsigned*)W1Flo, b1, Dp, Tp);
    k2_pairs<<<1024, 256, 0, stream>>>(Dp, Tp, pos, neg, (const unsigned*)W2Fhi,
                                       (const unsigned*)W2Flo, b2, W3, partials);
    k3_final<<<1, 64, 0, stream>>>(partials, out);
}

// Round 20
// 55.706 us; speedup vs baseline: 1.6577x; 1.0745x over previous
//
#include <hip/hip_runtime.h>

#define EMB 512
#define NROWS 10000
#define NPAIRS 65536

typedef __bf16 bf16x8 __attribute__((ext_vector_type(8)));
typedef float  f32x4  __attribute__((ext_vector_type(4)));
typedef unsigned int u32x4 __attribute__((ext_vector_type(4)));

// Split fp32 pair into packed bf16-hi dword and bf16-lo dword (RNE both).
__device__ __forceinline__ void split2(float x0, float x1, unsigned* hw, unsigned* lw) {
    unsigned u0 = __float_as_uint(x0), u1 = __float_as_uint(x1);
    unsigned r0 = u0 + 0x7FFFu + ((u0 >> 16) & 1u);
    unsigned r1 = u1 + 0x7FFFu + ((u1 >> 16) & 1u);
    float h0 = __uint_as_float(r0 & 0xFFFF0000u);
    float h1 = __uint_as_float(r1 & 0xFFFF0000u);
    float l0 = x0 - h0, l1 = x1 - h1;                 // exact
    unsigned v0 = __float_as_uint(l0), v1 = __float_as_uint(l1);
    unsigned s0 = v0 + 0x7FFFu + ((v0 >> 16) & 1u);
    unsigned s1 = v1 + 0x7FFFu + ((v1 >> 16) & 1u);
    *hw = (r0 >> 16) | (r1 & 0xFFFF0000u);
    *lw = (s0 >> 16) | (s1 & 0xFFFF0000u);
}

// ---------------- Kernel 0: pre-fragment W1 and W2 into MFMA lane-order bf16 hi/lo ----------
__global__ __launch_bounds__(256)
void k0_fragment(const float* __restrict__ W1, const float* __restrict__ W2,
                 unsigned short* __restrict__ W1Fhi, unsigned short* __restrict__ W1Flo,
                 unsigned short* __restrict__ W2Fhi, unsigned short* __restrict__ W2Flo)
{
    int e = blockIdx.x * 256 + threadIdx.x;
    float x;
    unsigned short *hp, *lp;
    if (e < 131072) {
        int i  = e & 7;
        int l  = (e >> 3) & 63;
        int nt = (e >> 9) & 7;
        int kt = (e >> 12) & 15;
        int t  = e >> 16;
        int k = kt * 32 + 8 * (l >> 4) + i;
        int n = nt * 16 + (l & 15);
        x = W1[(t * 512 + k) * 128 + n];
        hp = W1Fhi + e; lp = W1Flo + e;
    } else {
        int e2 = e - 131072;
        int i  = e2 & 7;
        int l  = (e2 >> 3) & 63;
        int nt = (e2 >> 9) & 3;
        int kt = e2 >> 11;
        int k = kt * 32 + 8 * (l >> 4) + i;
        int n = nt * 16 + (l & 15);
        x = W2[k * 64 + n];
        hp = W2Fhi + e2; lp = W2Flo + e2;
    }
    unsigned u = __float_as_uint(x);
    unsigned r = u + 0x7FFFu + ((u >> 16) & 1u);
    float hf = __uint_as_float(r & 0xFFFF0000u);
    float lf = x - hf;
    unsigned v = __float_as_uint(lf);
    unsigned s = v + 0x7FFFu + ((v >> 16) & 1u);
    *hp = (unsigned short)(r >> 16);
    *lp = (unsigned short)(s >> 16);
}

// ---------------- Kernel 1: R15 best-measured — B-in-regs streaming GEMM ----------------
#define K1_RPB 79
#define K1_NCH 5

__global__ __launch_bounds__(256, 2)
void k1_mfma(const float* __restrict__ drug, const float* __restrict__ tgt,
             const unsigned* __restrict__ W1Fhi, const unsigned* __restrict__ W1Flo,
             const float* __restrict__ b1,
             float* __restrict__ D, float* __restrict__ T)
{
    __shared__ unsigned short Ah[2][16][512];
    __shared__ unsigned short Al[2][16][512];

    int bid = blockIdx.x, tid = threadIdx.x;
    int t  = bid & 1;
    int ch = (bid >> 1) & 1;
    int rg = bid >> 2;
    const float* emb = t ? tgt : drug;
    float* out = t ? T : D;
    int row_base = rg * K1_RPB;

    int wave = tid >> 6, lane = tid & 63;
    int g = lane >> 4, lm = lane & 15;
    int nt = ch * 4 + wave;

    const u32x4* BH = (const u32x4*)W1Fhi + (t ? 8192 : 0);
    const u32x4* BL = (const u32x4*)W1Flo + (t ? 8192 : 0);

    u32x4 bhv[16], blv[16];
    #pragma unroll
    for (int kt = 0; kt < 16; kt++) {
        bhv[kt] = BH[(kt * 8 + nt) * 64 + lane];
        blv[kt] = BL[(kt * 8 + nt) * 64 + lane];
    }
    float bias = t ? 0.f : b1[nt * 16 + lm];

    float4 va[4][2];
    #pragma unroll
    for (int i = 0; i < 4; i++) {
        int gr = row_base + wave * 4 + i;
        if (gr > NROWS - 1) gr = NROWS - 1;
        const float* src = emb + (size_t)gr * EMB + lane * 8;
        va[i][0] = *(const float4*)src;
        va[i][1] = *(const float4*)(src + 4);
    }

    #pragma unroll
    for (int c = 0; c < K1_NCH; c++) {
        float4 vb[4][2];
        if (c + 1 < K1_NCH) {
            #pragma unroll
            for (int i = 0; i < 4; i++) {
                int gr = row_base + (c + 1) * 16 + wave * 4 + i;
                if (gr > NROWS - 1) gr = NROWS - 1;
                const float* src = emb + (size_t)gr * EMB + lane * 8;
                vb[i][0] = *(const float4*)src;
                vb[i][1] = *(const float4*)(src + 4);
            }
        }
        #pragma unroll
        for (int i = 0; i < 4; i++) {
            int lr = wave * 4 + i;
            unsigned h0, h1, h2, h3, l0, l1, l2, l3;
            split2(va[i][0].x, va[i][0].y, &h0, &l0);
            split2(va[i][0].z, va[i][0].w, &h1, &l1);
            split2(va[i][1].x, va[i][1].y, &h2, &l2);
            split2(va[i][1].z, va[i][1].w, &h3, &l3);
            u32x4 hq, lq;
            hq[0]=h0; hq[1]=h1; hq[2]=h2; hq[3]=h3;
            lq[0]=l0; lq[1]=l1; lq[2]=l2; lq[3]=l3;
            int cc = lane ^ (lr & 7);
            *(u32x4*)((char*)&Ah[c & 1][0][0] + lr * 1024 + cc * 16) = hq;
            *(u32x4*)((char*)&Al[c & 1][0][0] + lr * 1024 + cc * 16) = lq;
        }
        __syncthreads();
        f32x4 acc;
        acc[0]=0.f; acc[1]=0.f; acc[2]=0.f; acc[3]=0.f;
        #pragma unroll
        for (int kt = 0; kt < 16; kt++) {
            int cc = (kt * 4 + g) ^ (lm & 7);
            u32x4 ahq = *(const u32x4*)((const char*)&Ah[c & 1][0][0] + lm * 1024 + cc * 16);
            u32x4 alq = *(const u32x4*)((const char*)&Al[c & 1][0][0] + lm * 1024 + cc * 16);
            bf16x8 Af = __builtin_bit_cast(bf16x8, ahq);
            bf16x8 Alf = __builtin_bit_cast(bf16x8, alq);
            bf16x8 Bh = __builtin_bit_cast(bf16x8, bhv[kt]);
            bf16x8 Bl = __builtin_bit_cast(bf16x8, blv[kt]);
            acc = __builtin_amdgcn_mfma_f32_16x16x32_bf16(Af, Bh, acc, 0, 0, 0);
            acc = __builtin_amdgcn_mfma_f32_16x16x32_bf16(Af, Bl, acc, 0, 0, 0);
            acc = __builtin_amdgcn_mfma_f32_16x16x32_bf16(Alf, Bh, acc, 0, 0, 0);
        }
        #pragma unroll
        for (int reg = 0; reg < 4; reg++) {
            int lr = c * 16 + 4 * g + reg;
            int row = row_base + lr;
            if (lr < K1_RPB && row < NROWS)
                out[row * 128 + nt * 16 + lm] = acc[reg] + bias;
        }
        #pragma unroll
        for (int i = 0; i < 4; i++) { va[i][0] = vb[i][0]; va[i][1] = vb[i][1]; }
    }
}

// ---------------- Kernel 2: pair loss, counted-vmcnt pipelined gathers ----------------
// 2048 blocks x 4 independent waves, 16 pairs/wave = 48 physical rows (16 d + 32 t) per
// 32-k slice (6 KB), double-buffered (2 x 6 KB/wave = 48 KB/block, 3 blocks/CU kept).
// Per kt: {issue B(kt+1) 8 loads; lgkmcnt(0); issue 6 DMA(kt+1) -> buf^1; vmcnt(14) —
// kt's 14 ops drained, kt+1's fly; ds_read buf[kt&1]; split; 24 MFMA}. Fully unrolled.
__global__ __launch_bounds__(256)
void k2_pairs(const float* __restrict__ D, const float* __restrict__ T,
              const int* __restrict__ pos, const int* __restrict__ neg,
              const unsigned* __restrict__ W2Fhi, const unsigned* __restrict__ W2Flo,
              const float* __restrict__ b2, const float* __restrict__ W3,
              double* __restrict__ partials)
{
    __shared__ u32x4 Ash[4][2][384];   // 48 KB: per-wave 2 x 6 KB = 48 rows x 8 chunks

    int tid = threadIdx.x;
    int wave = tid >> 6, lane = tid & 63;
    int g = lane >> 4, lm = lane & 15;
    int rr = lane >> 3, cc = lane & 7;
    int gw = blockIdx.x * 4 + wave;              // 0..8191
    const int* pairs = (gw < 4096) ? pos : neg;  // blocks 0..1023 pos, 1024..2047 neg
    int p0 = (gw & 4095) * 16;                   // 16 pairs per wave

    // DMA it covers rows pr = it*8 + rr: pr<16 -> d-row of pair pr; else t-row of out-row pr-16
    const float* bp[6];
    #pragma unroll
    for (int it = 0; it < 6; it++) {
        int pr = it * 8 + rr;
        int idxv;
        const float* src;
        if (pr < 16) { idxv = pairs[(p0 + pr) * 3]; src = D; }
        else { int q = pr - 16; idxv = pairs[(p0 + (q >> 1)) * 3 + 1 + (q & 1)]; src = T; }
        bp[it] = src + (size_t)idxv * 128 + ((cc ^ (pr & 7)) << 2);
    }

    const u32x4* BH4 = (const u32x4*)W2Fhi;
    const u32x4* BL4 = (const u32x4*)W2Flo;

    f32x4 acc[2][4];
    #pragma unroll
    for (int mt = 0; mt < 2; mt++)
        #pragma unroll
        for (int nt = 0; nt < 4; nt++) { acc[mt][nt][0]=0.f; acc[mt][nt][1]=0.f; acc[mt][nt][2]=0.f; acc[mt][nt][3]=0.f; }

    // ---- prologue: B(0) 8 loads + DMA(0) 6 -> 14 ops in flight ----
    u32x4 bhc[4], blc[4];
    #pragma unroll
    for (int nt = 0; nt < 4; nt++) {
        bhc[nt] = BH4[(0 * 4 + nt) * 64 + lane];
        blc[nt] = BL4[(0 * 4 + nt) * 64 + lane];
    }
    #pragma unroll
    for (int it = 0; it < 6; it++)
        __builtin_amdgcn_global_load_lds(
            (const __attribute__((address_space(1))) void*)(bp[it]),
            (__attribute__((address_space(3))) void*)((char*)&Ash[wave][0][0] + it * 1024),
            16, 0, 0);

    #pragma unroll
    for (int kt = 0; kt < 4; kt++) {
        u32x4 bhn[4], bln[4];
        if (kt < 3) {   // compile-time under full unroll
            #pragma unroll
            for (int nt = 0; nt < 4; nt++) {
                bhn[nt] = BH4[((kt + 1) * 4 + nt) * 64 + lane];
                bln[nt] = BL4[((kt + 1) * 4 + nt) * 64 + lane];
            }
            // ds_reads of buf[(kt+1)&1] (issued in iter kt-1) retired before overwrite
            asm volatile("s_waitcnt lgkmcnt(0)" ::: "memory");
            #pragma unroll
            for (int it = 0; it < 6; it++)
                __builtin_amdgcn_global_load_lds(
                    (const __attribute__((address_space(1))) void*)(bp[it] + (kt + 1) * 32),
                    (__attribute__((address_space(3))) void*)((char*)&Ash[wave][(kt + 1) & 1][0] + it * 1024),
                    16, 0, 0);
            asm volatile("s_waitcnt vmcnt(14)" ::: "memory");  // kt's 14 drained; kt+1's fly
        } else {
            asm volatile("s_waitcnt vmcnt(0)" ::: "memory");
        }
        const u32x4* A4w = &Ash[wave][kt & 1][0];
        #pragma unroll
        for (int mt = 0; mt < 2; mt++) {
            int r = mt * 16 + lm;            // output row 0..31
            int p = r >> 1;                  // d-row 0..15
            int ds = p & 7, ts = r & 7;      // (16+r)&7 == r&7
            const f32x4* drow = (const f32x4*)(A4w + p * 8);
            const f32x4* trow = (const f32x4*)(A4w + (16 + r) * 8);
            f32x4 d0 = drow[(2 * g) ^ ds];
            f32x4 d1 = drow[(2 * g + 1) ^ ds];
            f32x4 t0 = trow[(2 * g) ^ ts];
            f32x4 t1 = trow[(2 * g + 1) ^ ts];
            float h0 = fmaxf(d0[0] + t0[0], 0.f), h1v = fmaxf(d0[1] + t0[1], 0.f);
            float h2 = fmaxf(d0[2] + t0[2], 0.f), h3 = fmaxf(d0[3] + t0[3], 0.f);
            float h4 = fmaxf(d1[0] + t1[0], 0.f), h5 = fmaxf(d1[1] + t1[1], 0.f);
            float h6 = fmaxf(d1[2] + t1[2], 0.f), h7 = fmaxf(d1[3] + t1[3], 0.f);
            unsigned hq0, hq1, hq2, hq3, lq0, lq1, lq2, lq3;
            split2(h0, h1v, &hq0, &lq0);
            split2(h2, h3,  &hq1, &lq1);
            split2(h4, h5,  &hq2, &lq2);
            split2(h6, h7,  &hq3, &lq3);
            u32x4 ah, al;
            ah[0]=hq0; ah[1]=hq1; ah[2]=hq2; ah[3]=hq3;
            al[0]=lq0; al[1]=lq1; al[2]=lq2; al[3]=lq3;
            bf16x8 Ahf = __builtin_bit_cast(bf16x8, ah);
            bf16x8 Alf = __builtin_bit_cast(bf16x8, al);
            #pragma unroll
            for (int nt = 0; nt < 4; nt++) {
                bf16x8 Bh = __builtin_bit_cast(bf16x8, bhc[nt]);
                bf16x8 Bl = __builtin_bit_cast(bf16x8, blc[nt]);
                acc[mt][nt] = __builtin_amdgcn_mfma_f32_16x16x32_bf16(Ahf, Bh, acc[mt][nt], 0, 0, 0);
                acc[mt][nt] = __builtin_amdgcn_mfma_f32_16x16x32_bf16(Ahf, Bl, acc[mt][nt], 0, 0, 0);
                acc[mt][nt] = __builtin_amdgcn_mfma_f32_16x16x32_bf16(Alf, Bh, acc[mt][nt], 0, 0, 0);
            }
        }
        // rotate B pipeline registers
        #pragma unroll
        for (int nt = 0; nt < 4; nt++) { bhc[nt] = bhn[nt]; blc[nt] = bln[nt]; }
    }

    // ---- epilogue: layer 3 + pair diff (C row = mt*16+4g+reg, col = nt*16+lm) ----
    float b2v[4], w3v[4];
    #pragma unroll
    for (int nt = 0; nt < 4; nt++) { b2v[nt] = b2[nt * 16 + lm]; w3v[nt] = W3[nt * 16 + lm]; }

    float pr[2][4];
    #pragma unroll
    for (int mt = 0; mt < 2; mt++)
        #pragma unroll
        for (int reg = 0; reg < 4; reg++) {
            float s = 0.f;
            #pragma unroll
            for (int nt = 0; nt < 4; nt++) {
                float h2 = fmaxf(acc[mt][nt][reg] + b2v[nt], 0.f);
                s = fmaf(h2, w3v[nt], s);
            }
            pr[mt][reg] = s;
        }
    #pragma unroll
    for (int m = 1; m <= 8; m <<= 1)
        #pragma unroll
        for (int mt = 0; mt < 2; mt++)
            #pragma unroll
            for (int reg = 0; reg < 4; reg++)
                pr[mt][reg] += __shfl_xor(pr[mt][reg], m, 64);

    double dsq = 0.0;
    #pragma unroll
    for (int mt = 0; mt < 2; mt++) {
        float d0 = pr[mt][0] - pr[mt][1];
        float d1 = pr[mt][2] - pr[mt][3];
        dsq += (double)d0 * (double)d0 + (double)d1 * (double)d1;
    }
    dsq += __shfl_xor(dsq, 16, 64);
    dsq += __shfl_xor(dsq, 32, 64);

    __syncthreads();
    if (lane == 0) ((double*)&Ash[wave][0][0])[0] = dsq;
    __syncthreads();
    if (tid == 0) {
        double sum = 0.0;
        #pragma unroll
        for (int w = 0; w < 4; w++) sum += ((double*)&Ash[w][0][0])[0];
        partials[blockIdx.x] = sum;   // 0..1023 pos, 1024..2047 neg
    }
}

// ---------------- Kernel 3: final reduction (2048 partials) ----------------
__global__ void k3_final(const double* __restrict__ partials, float* __restrict__ out)
{
    int lane = threadIdx.x;  // 64 threads
    double sp = 0.0, sn = 0.0;
    #pragma unroll
    for (int i = 0; i < 16; i++) {
        sp += partials[lane + 64 * i];
        sn += partials[1024 + lane + 64 * i];
    }
    #pragma unroll
    for (int m = 1; m <= 32; m <<= 1) {
        sp += __shfl_xor(sp, m, 64);
        sn += __shfl_xor(sn, m, 64);
    }
    if (lane == 0) out[0] = (float)((sp - sn) / (double)NPAIRS);
}

extern "C" void kernel_launch(void* const* d_in, const int* in_sizes, int n_in,
                              void* d_out, int out_size, void* d_ws, size_t ws_size,
                              hipStream_t stream) {
    const int*   pos  = (const int*)d_in[0];
    const int*   neg  = (const int*)d_in[1];
    const float* drug = (const float*)d_in[2];
    const float* tgt  = (const float*)d_in[3];
    const float* W1   = (const float*)d_in[4];
    const float* b1   = (const float*)d_in[5];
    const float* W2   = (const float*)d_in[6];
    const float* b2   = (const float*)d_in[7];
    const float* W3   = (const float*)d_in[8];
    // d_in[9] = b3: cancels in a1 - a2, unused

    float* Dp = (float*)d_ws;                                 // 5.12 MB
    float* Tp = Dp + NROWS * 128;                             // 5.12 MB
    char* base = (char*)(Tp + NROWS * 128);
    unsigned short* W2Fhi = (unsigned short*)base;            // 16 KB
    unsigned short* W2Flo = W2Fhi + 8192;                     // 16 KB
    unsigned short* W1Fhi = W2Flo + 8192;                     // 256 KB
    unsigned short* W1Flo = W1Fhi + 131072;                   // 256 KB
    double* partials = (double*)(W1Flo + 131072);             // 16 KB
    float* out = (float*)d_out;

    k0_fragment<<<544, 256, 0, stream>>>(W1, W2, W1Fhi, W1Flo, W2Fhi, W2Flo);
    k1_mfma<<<512, 256, 0, stream>>>(drug, tgt, (const unsigned*)W1Fhi,
                                     (const unsigned*)W1Flo, b1, Dp, Tp);
    k2_pairs<<<2048, 256, 0, stream>>>(Dp, Tp, pos, neg, (const unsigned*)W2Fhi,
                                       (const unsigned*)W2Flo, b2, W3, partials);
    k3_final<<<1, 64, 0, stream>>>(partials, out);
}